// Round 1
// baseline (992.549 us; speedup 1.0000x reference)
//
#include <hip/hip_runtime.h>

// ============================================================================
// ps_component: FPN head. c[b,w] per level = sum_{cout,h} w_t[cout]*w_pl[h]*
//   relu(conv3x3(p)[b,cout,h,w] + b_s[cout])  + const, fused into one kernel
//   per level via implicit-GEMM bf16 MFMA (16x16x32). Level 4 (p5) is a pure
//   linear reduction. Output [64,240] fp32 assembled via atomicAdd on top of
//   an init kernel that writes the constant term.
// ============================================================================

typedef short s8v __attribute__((ext_vector_type(8)));   // 8 x bf16 bits
typedef float f4v __attribute__((ext_vector_type(4)));

__device__ __forceinline__ unsigned short f32_bf16_rne(float f) {
  union { float f; unsigned int u; } v;
  v.f = f;
  unsigned int u = v.u;
  u += 0x7FFFu + ((u >> 16) & 1u);
  return (unsigned short)(u >> 16);
}

// ---------------- weight prep: fp32 OIHW -> bf16 [tap][cout][cin] -----------
__global__ void prep_weights_k(const float* __restrict__ w1,
                               const float* __restrict__ w2,
                               const float* __restrict__ w3,
                               unsigned short* __restrict__ wbf) {
  int idx = blockIdx.x * 256 + threadIdx.x;
  const int per = 9 * 128 * 128;
  if (idx >= 3 * per) return;
  int s = idx / per;
  int r = idx - s * per;
  int tap  = r >> 14;          // r / (128*128)
  int cout = (r >> 7) & 127;
  int cin  = r & 127;
  int kh = tap / 3, kw = tap - kh * 3;
  const float* w = (s == 0) ? w1 : ((s == 1) ? w2 : w3);
  float val = w[((cout * 128 + cin) * 3 + kh) * 3 + kw];
  wbf[idx] = f32_bf16_rne(val);
}

// ---------------- init: out[b,c] = b_t * sum_h w_pl[h] + b_pl ---------------
__global__ void init_out_k(float* __restrict__ out,
                           const float* bt1, const float* bt2,
                           const float* bt3, const float* bt4,
                           const float* wpl1, const float* bpl1,
                           const float* wpl2, const float* bpl2,
                           const float* wpl3, const float* bpl3,
                           const float* wpl4, const float* bpl4) {
  int idx = blockIdx.x * 256 + threadIdx.x;
  if (idx >= 64 * 240) return;
  int c = idx % 240;
  const float* wpl; const float* bpl; const float* bt; int H;
  if (c < 128)      { wpl = wpl1; bpl = bpl1; bt = bt1; H = 64; }
  else if (c < 192) { wpl = wpl2; bpl = bpl2; bt = bt2; H = 32; }
  else if (c < 224) { wpl = wpl3; bpl = bpl3; bt = bt3; H = 16; }
  else              { wpl = wpl4; bpl = bpl4; bt = bt4; H = 8;  }
  float s = 0.f;
  for (int h = 0; h < H; ++h) s += wpl[h];
  out[idx] = bt[0] * s + bpl[0];
}

// ---------------- level 4: pure linear reduction over p5 --------------------
__global__ void level4_k(const float* __restrict__ p5,
                         const float* __restrict__ w_t4,
                         const float* __restrict__ w_pl4,
                         float* __restrict__ out) {
  int b = blockIdx.x;
  int t = threadIdx.x;
  int w = t & 15, g = t >> 4;                 // g in [0,16)
  const float* base = p5 + (size_t)b * 65536; // 512*8*16
  float acc = 0.f;
  for (int j = g; j < 4096; j += 16) {        // j = c*8 + h
    int c = j >> 3, h = j & 7;
    acc += w_t4[c] * w_pl4[h] * base[j * 16 + w];
  }
  acc += __shfl_xor(acc, 16);
  acc += __shfl_xor(acc, 32);
  if ((t & 48) == 0) atomicAdd(&out[b * 240 + 224 + w], acc);
}

// ---------------- fused conv3x3+relu+tidy+pool per level --------------------
// Block: 256 thr (4 waves). M=128 couts x N=128 spatial (R rows x W cols).
// K = 4 cin-chunks(32) x 9 taps via mfma_f32_16x16x32_bf16.
// LDS: X tile [R+2][W+2][cin32 pad40] (transposed, bf16), W tile [3 kw][128][40].
template<int H, int W, int R, int COLBASE>
__global__ __launch_bounds__(256, 2)
void conv_level_k(const float* __restrict__ p,
                  const unsigned short* __restrict__ wbf,   // [9][128][128] bf16
                  const float* __restrict__ b_s,
                  const float* __restrict__ w_t,
                  const float* __restrict__ w_pl,
                  float* __restrict__ out) {
  constexpr int ROWS = R + 2;
  constexpr int WP = W + 2;
  constexpr int CS = 40;                      // cin stride (bf16) in LDS
  constexpr int HW = H * W;
  __shared__ unsigned short Xs[ROWS * WP * CS];
  __shared__ unsigned short Ws[3 * 128 * CS];

  const int tid  = threadIdx.x;
  const int wave = tid >> 6;
  const int lane = tid & 63;
  const int lm = lane & 15;
  const int q  = lane >> 4;
  const int q8 = q * 8;
  const int h0 = blockIdx.x * R;
  const int b  = blockIdx.y;

  int rr[2], ww[2];
#pragma unroll
  for (int nt = 0; nt < 2; ++nt) {
    int n = wave * 32 + nt * 16 + lm;
    rr[nt] = n / W;
    ww[nt] = n % W;
  }

  f4v acc[8][2];
#pragma unroll
  for (int mt = 0; mt < 8; ++mt)
#pragma unroll
    for (int nt = 0; nt < 2; ++nt)
      acc[mt][nt] = (f4v){0.f, 0.f, 0.f, 0.f};

  const float* pb = p + (size_t)b * 128 * HW;

  for (int chunk = 0; chunk < 4; ++chunk) {
    for (int kh = 0; kh < 3; ++kh) {
      __syncthreads();
      if (kh == 0) {
        // stage X chunk: ROWS*WP*4 items, each 8 cin -> one ds_write_b128
        for (int t = tid; t < ROWS * WP * 4; t += 256) {
          int w_in = t % WP;
          int cg   = (t / WP) & 3;
          int row  = t / (WP * 4);
          int h_in = h0 + row - 1;
          int w_g  = w_in - 1;
          s8v v8;
          if (h_in >= 0 && h_in < H && w_g >= 0 && w_g < W) {
            const float* src = pb + (size_t)(chunk * 32 + cg * 8) * HW + h_in * W + w_g;
#pragma unroll
            for (int i = 0; i < 8; ++i)
              v8[i] = (short)f32_bf16_rne(src[i * HW]);
          } else {
#pragma unroll
            for (int i = 0; i < 8; ++i) v8[i] = 0;
          }
          *(s8v*)&Xs[(row * WP + w_in) * CS + cg * 8] = v8;
        }
      }
      // stage 3 kw taps of weights for this (chunk, kh): 3*128*4 items of 16B
      for (int t = tid; t < 3 * 128 * 4; t += 256) {
        int cg   = t & 3;
        int cout = (t >> 2) & 127;
        int kw   = t >> 9;
        const unsigned short* src =
            wbf + ((kh * 3 + kw) * 128 + cout) * 128 + chunk * 32 + cg * 8;
        *(s8v*)&Ws[(kw * 128 + cout) * CS + cg * 8] = *(const s8v*)src;
      }
      __syncthreads();
#pragma unroll
      for (int kw = 0; kw < 3; ++kw) {
        s8v bf[2];
#pragma unroll
        for (int nt = 0; nt < 2; ++nt)
          bf[nt] = *(const s8v*)&Xs[((rr[nt] + kh) * WP + ww[nt] + kw) * CS + q8];
#pragma unroll
        for (int mt = 0; mt < 8; ++mt) {
          s8v af = *(const s8v*)&Ws[(kw * 128 + mt * 16 + lm) * CS + q8];
          acc[mt][0] = __builtin_amdgcn_mfma_f32_16x16x32_bf16(af, bf[0], acc[mt][0], 0, 0, 0);
          acc[mt][1] = __builtin_amdgcn_mfma_f32_16x16x32_bf16(af, bf[1], acc[mt][1], 0, 0, 0);
        }
      }
    }
  }

  // epilogue: bias+relu+tidy weight, pool weight, quad-reduce, atomic add
#pragma unroll
  for (int nt = 0; nt < 2; ++nt) {
    float s = 0.f;
#pragma unroll
    for (int mt = 0; mt < 8; ++mt) {
#pragma unroll
      for (int rg = 0; rg < 4; ++rg) {
        int cout = mt * 16 + q * 4 + rg;
        float v = acc[mt][nt][rg] + b_s[cout];
        v = fmaxf(v, 0.f);
        s = fmaf(w_t[cout], v, s);
      }
    }
    s *= w_pl[h0 + rr[nt]];
    s += __shfl_xor(s, 16);
    s += __shfl_xor(s, 32);
    if (lane < 16) atomicAdd(&out[b * 240 + COLBASE + ww[nt]], s);
  }
}

// ============================================================================
extern "C" void kernel_launch(void* const* d_in, const int* in_sizes, int n_in,
                              void* d_out, int out_size, void* d_ws, size_t ws_size,
                              hipStream_t stream) {
  (void)in_sizes; (void)n_in; (void)out_size; (void)ws_size;
  const float* p2   = (const float*)d_in[0];
  const float* p3   = (const float*)d_in[1];
  const float* p4   = (const float*)d_in[2];
  const float* p5   = (const float*)d_in[3];
  const float* w_s1 = (const float*)d_in[4];
  const float* b_s1 = (const float*)d_in[5];
  const float* w_s2 = (const float*)d_in[6];
  const float* b_s2 = (const float*)d_in[7];
  const float* w_s3 = (const float*)d_in[8];
  const float* b_s3 = (const float*)d_in[9];
  const float* w_t1 = (const float*)d_in[10];
  const float* b_t1 = (const float*)d_in[11];
  const float* w_t2 = (const float*)d_in[12];
  const float* b_t2 = (const float*)d_in[13];
  const float* w_t3 = (const float*)d_in[14];
  const float* b_t3 = (const float*)d_in[15];
  const float* w_t4 = (const float*)d_in[16];
  const float* b_t4 = (const float*)d_in[17];
  const float* w_pl1 = (const float*)d_in[18];
  const float* b_pl1 = (const float*)d_in[19];
  const float* w_pl2 = (const float*)d_in[20];
  const float* b_pl2 = (const float*)d_in[21];
  const float* w_pl3 = (const float*)d_in[22];
  const float* b_pl3 = (const float*)d_in[23];
  const float* w_pl4 = (const float*)d_in[24];
  const float* b_pl4 = (const float*)d_in[25];

  unsigned short* wbf = (unsigned short*)d_ws;  // 3 * 9*128*128 bf16 = 884736 B
  float* out = (float*)d_out;

  const int per = 9 * 128 * 128;
  prep_weights_k<<<dim3((3 * per + 255) / 256), dim3(256), 0, stream>>>(w_s1, w_s2, w_s3, wbf);
  init_out_k<<<dim3(60), dim3(256), 0, stream>>>(out, b_t1, b_t2, b_t3, b_t4,
                                                 w_pl1, b_pl1, w_pl2, b_pl2,
                                                 w_pl3, b_pl3, w_pl4, b_pl4);
  conv_level_k<64, 128, 1, 0><<<dim3(64, 64), dim3(256), 0, stream>>>(
      p2, wbf, b_s1, w_t1, w_pl1, out);
  conv_level_k<32, 64, 2, 128><<<dim3(16, 64), dim3(256), 0, stream>>>(
      p3, wbf + per, b_s2, w_t2, w_pl2, out);
  conv_level_k<16, 32, 4, 192><<<dim3(4, 64), dim3(256), 0, stream>>>(
      p4, wbf + 2 * per, b_s3, w_t3, w_pl3, out);
  level4_k<<<dim3(64), dim3(256), 0, stream>>>(p5, w_t4, w_pl4, out);
}

// Round 2
// 701.279 us; speedup vs baseline: 1.4153x; 1.4153x over previous
//
#include <hip/hip_runtime.h>

// ============================================================================
// ps_component round 2: bf16-relayout prepass + DMA-staged implicit-GEMM conv.
//  - prep_x: fp32 NCHW -> bf16 [b][chunk4][qg4][H][W][8cin] (16B cin blocks)
//  - prep_w: fp32 OIHW -> bf16 [lvl][chunk][kh][kw][qg][cout][8cin]
//  - conv_level_k: X and W staged to LDS via global_load_lds dwordx4;
//    LDS layouts [qg][row][pos][16B] / [kw][qg][cout][16B] are bank-uniform
//    (pos stride = 4 banks) -> conflict-free reads. nt=4, N=256/block.
// ============================================================================

typedef short s8v __attribute__((ext_vector_type(8)));   // 8 x bf16 bits
typedef float f4v __attribute__((ext_vector_type(4)));

__device__ __forceinline__ unsigned short f32_bf16_rne(float f) {
  union { float f; unsigned int u; } v;
  v.f = f;
  unsigned int u = v.u;
  u += 0x7FFFu + ((u >> 16) & 1u);
  return (unsigned short)(u >> 16);
}

__device__ __forceinline__ void gld_lds16(const unsigned short* g, unsigned short* l) {
  __builtin_amdgcn_global_load_lds(
      (const __attribute__((address_space(1))) unsigned int*)g,
      (__attribute__((address_space(3))) unsigned int*)l, 16, 0, 0);
}

// ---------------- prep X: NCHW fp32 -> [b][chunk][qg][H][W][8c] bf16 --------
__global__ void prep_x_k(const float* __restrict__ p,
                         unsigned short* __restrict__ out,
                         int H, int W) {
  size_t idx = (size_t)blockIdx.x * 256 + threadIdx.x;  // one 16B block each
  int HW = H * W;
  int w = (int)(idx % W);
  size_t r = idx / W;
  int h = (int)(r % H); r /= H;
  int qg = (int)(r & 3); r >>= 2;
  int chunk = (int)(r & 3); r >>= 2;
  int b = (int)r;
  const float* src = p + (((size_t)(b * 128 + chunk * 32 + qg * 8)) * H + h) * W + w;
  s8v v;
#pragma unroll
  for (int i = 0; i < 8; ++i) v[i] = (short)f32_bf16_rne(src[(size_t)i * HW]);
  *(s8v*)(out + idx * 8) = v;
}

// ---------------- prep W: OIHW fp32 -> [s][chunk][kh][kw][qg][cout][8c] -----
__global__ void prep_w_k(const float* __restrict__ w1,
                         const float* __restrict__ w2,
                         const float* __restrict__ w3,
                         unsigned short* __restrict__ out) {
  int idx = blockIdx.x * 256 + threadIdx.x;   // total 3*4*3*3*4*128*8 = 442368
  if (idx >= 442368) return;
  int i    = idx & 7;
  int cout = (idx >> 3) & 127;
  int t    = idx >> 10;
  int qg = t & 3; t >>= 2;
  int kw = t % 3; t /= 3;
  int kh = t % 3; t /= 3;
  int chunk = t & 3; t >>= 2;
  int s = t;
  const float* w = (s == 0) ? w1 : ((s == 1) ? w2 : w3);
  int cin = chunk * 32 + qg * 8 + i;
  out[idx] = f32_bf16_rne(w[((cout * 128 + cin) * 3 + kh) * 3 + kw]);
}

// ---------------- init: out[b,c] = b_t * sum_h w_pl[h] + b_pl ---------------
__global__ void init_out_k(float* __restrict__ out,
                           const float* bt1, const float* bt2,
                           const float* bt3, const float* bt4,
                           const float* wpl1, const float* bpl1,
                           const float* wpl2, const float* bpl2,
                           const float* wpl3, const float* bpl3,
                           const float* wpl4, const float* bpl4) {
  int idx = blockIdx.x * 256 + threadIdx.x;
  if (idx >= 64 * 240) return;
  int c = idx % 240;
  const float* wpl; const float* bpl; const float* bt; int H;
  if (c < 128)      { wpl = wpl1; bpl = bpl1; bt = bt1; H = 64; }
  else if (c < 192) { wpl = wpl2; bpl = bpl2; bt = bt2; H = 32; }
  else if (c < 224) { wpl = wpl3; bpl = bpl3; bt = bt3; H = 16; }
  else              { wpl = wpl4; bpl = bpl4; bt = bt4; H = 8;  }
  float s = 0.f;
  for (int h = 0; h < H; ++h) s += wpl[h];
  out[idx] = bt[0] * s + bpl[0];
}

// ---------------- level 4: pure linear reduction over p5 --------------------
__global__ void level4_k(const float* __restrict__ p5,
                         const float* __restrict__ w_t4,
                         const float* __restrict__ w_pl4,
                         float* __restrict__ out) {
  int b = blockIdx.x;
  int z = blockIdx.y;                          // c-range [z*128, z*128+128)
  int t = threadIdx.x;
  int w = t & 15, g = t >> 4;                  // g in [0,16)
  const float* base = p5 + (size_t)b * 65536 + z * 16384;
  const float* wt = w_t4 + z * 128;
  float acc = 0.f;
  for (int j = g; j < 1024; j += 16) {         // j = c_local*8 + h
    acc += wt[j >> 3] * w_pl4[j & 7] * base[j * 16 + w];
  }
  acc += __shfl_xor(acc, 16);
  acc += __shfl_xor(acc, 32);
  if ((t & 48) == 0) atomicAdd(&out[b * 240 + 224 + w], acc);
}

// ---------------- fused conv3x3+relu+tidy+pool per level --------------------
// Block: 256 thr. M=128 couts x N=256 positions (R rows x W cols), nt=4.
// K = 4 chunks(32cin) x 9 taps, mfma_f32_16x16x32_bf16.
template<int H, int W, int R, int COLBASE>
__global__ __launch_bounds__(256, 2)
void conv_level_k(const unsigned short* __restrict__ xp,  // [b][4][4][H][W][8]
                  const unsigned short* __restrict__ wl,  // [4][3][3][4][128][8]
                  const float* __restrict__ b_s,
                  const float* __restrict__ w_t,
                  const float* __restrict__ w_pl,
                  float* __restrict__ out) {
  constexpr int ROWS = R + 2;
  constexpr int WP = W + 2;
  __shared__ __align__(16) unsigned short Xs[4][ROWS][WP][8];
  __shared__ __align__(16) unsigned short Ws[3][4][128][8];

  const int tid = threadIdx.x;
  const int wave = tid >> 6, lane = tid & 63;
  const int lm = lane & 15, q = lane >> 4;
  const int h0 = blockIdx.x * R;
  const int b  = blockIdx.y;

  int rr[4], ww[4], xbase[4];
#pragma unroll
  for (int nt = 0; nt < 4; ++nt) {
    int n = wave * 64 + nt * 16 + lm;
    rr[nt] = n / W;
    ww[nt] = n % W;
    xbase[nt] = ((q * ROWS + rr[nt]) * WP + ww[nt]) * 16;   // byte offset
  }
  const int woff = (q * 128 + lm) * 16;                      // af byte offset

  f4v acc[8][4];
#pragma unroll
  for (int mt = 0; mt < 8; ++mt)
#pragma unroll
    for (int nt = 0; nt < 4; ++nt)
      acc[mt][nt] = (f4v){0.f, 0.f, 0.f, 0.f};

  const s8v Z8 = {0, 0, 0, 0, 0, 0, 0, 0};
  // zero left/right halo slots once (never overwritten by DMA)
  for (int t = tid; t < 4 * ROWS * 2; t += 256) {
    int qg = t / (ROWS * 2);
    int r2 = t % (ROWS * 2);
    *(s8v*)&Xs[qg][r2 >> 1][(r2 & 1) ? (WP - 1) : 0][0] = Z8;
  }

  const unsigned short* xb = xp + (size_t)b * 16 * H * W * 8;
  unsigned short* WsF = &Ws[0][0][0][0];
  const char* XsB = (const char*)&Xs[0][0][0][0];
  const char* WsB = (const char*)WsF;

  for (int chunk = 0; chunk < 4; ++chunk) {
    __syncthreads();   // prior stage's reads done before overwriting Xs/Ws
    {  // stage X chunk: wave handles qg == wave
      const int qg = wave;
      const unsigned short* xq = xb + (size_t)(chunk * 4 + qg) * H * W * 8;
#pragma unroll
      for (int row = 0; row < ROWS; ++row) {
        int h_in = h0 + row - 1;
        bool ok = (h_in >= 0) && (h_in < H);
        const unsigned short* srow = xq + (size_t)h_in * W * 8;
        if constexpr (W >= 64) {
#pragma unroll
          for (int j = 0; j < W / 64; ++j) {
            if (ok) gld_lds16(srow + j * 512 + lane * 8, &Xs[qg][row][1 + j * 64][0]);
            else    *(s8v*)&Xs[qg][row][1 + j * 64 + lane][0] = Z8;
          }
        } else {
          if (lane < W) {
            s8v v = Z8;
            if (ok) v = *(const s8v*)(srow + lane * 8);
            *(s8v*)&Xs[qg][row][1 + lane][0] = v;
          }
        }
      }
    }
    for (int kh = 0; kh < 3; ++kh) {
      if (kh) __syncthreads();
      {  // stage W for (chunk, kh): 24 KB contiguous
        const unsigned short* wsrc = wl + (size_t)(chunk * 3 + kh) * 12288;
        for (int i2 = wave; i2 < 24; i2 += 4)
          gld_lds16(wsrc + i2 * 512 + lane * 8, WsF + i2 * 512);
      }
      __syncthreads();

      int xk[4];
#pragma unroll
      for (int nt = 0; nt < 4; ++nt) xk[nt] = xbase[nt] + kh * (WP * 16);

#pragma unroll
      for (int kw = 0; kw < 3; ++kw) {
        s8v bf[4];
#pragma unroll
        for (int nt = 0; nt < 4; ++nt)
          bf[nt] = *(const s8v*)(XsB + xk[nt] + kw * 16);
#pragma unroll
        for (int mt = 0; mt < 8; ++mt) {
          s8v af = *(const s8v*)(WsB + kw * 8192 + mt * 256 + woff);
#pragma unroll
          for (int nt = 0; nt < 4; ++nt)
            acc[mt][nt] = __builtin_amdgcn_mfma_f32_16x16x32_bf16(af, bf[nt], acc[mt][nt], 0, 0, 0);
        }
      }
    }
  }

  // epilogue: bias+relu+tidy weight, pool weight, quad-reduce, atomic add
#pragma unroll
  for (int nt = 0; nt < 4; ++nt) {
    float s = 0.f;
#pragma unroll
    for (int mt = 0; mt < 8; ++mt) {
#pragma unroll
      for (int rg = 0; rg < 4; ++rg) {
        int cout = mt * 16 + q * 4 + rg;
        float v = fmaxf(acc[mt][nt][rg] + b_s[cout], 0.f);
        s = fmaf(w_t[cout], v, s);
      }
    }
    s *= w_pl[h0 + rr[nt]];
    s += __shfl_xor(s, 16);
    s += __shfl_xor(s, 32);
    if (lane < 16) atomicAdd(&out[b * 240 + COLBASE + ww[nt]], s);
  }
}

// ============================================================================
extern "C" void kernel_launch(void* const* d_in, const int* in_sizes, int n_in,
                              void* d_out, int out_size, void* d_ws, size_t ws_size,
                              hipStream_t stream) {
  (void)in_sizes; (void)n_in; (void)out_size; (void)ws_size;
  const float* p2   = (const float*)d_in[0];
  const float* p3   = (const float*)d_in[1];
  const float* p4   = (const float*)d_in[2];
  const float* p5   = (const float*)d_in[3];
  const float* w_s1 = (const float*)d_in[4];
  const float* b_s1 = (const float*)d_in[5];
  const float* w_s2 = (const float*)d_in[6];
  const float* b_s2 = (const float*)d_in[7];
  const float* w_s3 = (const float*)d_in[8];
  const float* b_s3 = (const float*)d_in[9];
  const float* w_t1 = (const float*)d_in[10];
  const float* b_t1 = (const float*)d_in[11];
  const float* w_t2 = (const float*)d_in[12];
  const float* b_t2 = (const float*)d_in[13];
  const float* w_t3 = (const float*)d_in[14];
  const float* b_t3 = (const float*)d_in[15];
  const float* w_t4 = (const float*)d_in[16];
  const float* b_t4 = (const float*)d_in[17];
  const float* w_pl1 = (const float*)d_in[18];
  const float* b_pl1 = (const float*)d_in[19];
  const float* w_pl2 = (const float*)d_in[20];
  const float* b_pl2 = (const float*)d_in[21];
  const float* w_pl3 = (const float*)d_in[22];
  const float* b_pl3 = (const float*)d_in[23];
  const float* w_pl4 = (const float*)d_in[24];
  const float* b_pl4 = (const float*)d_in[25];

  // workspace layout (bytes): wp 884736 | xp1 134.2MB | xp2 33.5MB | xp3 8.4MB
  unsigned short* wp  = (unsigned short*)d_ws;
  unsigned short* xp1 = wp + 442368;
  unsigned short* xp2 = xp1 + (size_t)64 * 16 * 64 * 128 * 8;
  unsigned short* xp3 = xp2 + (size_t)64 * 16 * 32 * 64 * 8;
  float* out = (float*)d_out;

  prep_w_k<<<dim3(1728), dim3(256), 0, stream>>>(w_s1, w_s2, w_s3, wp);
  prep_x_k<<<dim3(32768), dim3(256), 0, stream>>>(p2, xp1, 64, 128);
  prep_x_k<<<dim3(8192),  dim3(256), 0, stream>>>(p3, xp2, 32, 64);
  prep_x_k<<<dim3(2048),  dim3(256), 0, stream>>>(p4, xp3, 16, 32);
  init_out_k<<<dim3(60), dim3(256), 0, stream>>>(out, b_t1, b_t2, b_t3, b_t4,
                                                 w_pl1, b_pl1, w_pl2, b_pl2,
                                                 w_pl3, b_pl3, w_pl4, b_pl4);
  conv_level_k<64, 128, 2, 0><<<dim3(32, 64), dim3(256), 0, stream>>>(
      xp1, wp, b_s1, w_t1, w_pl1, out);
  conv_level_k<32, 64, 4, 128><<<dim3(8, 64), dim3(256), 0, stream>>>(
      xp2, wp + 147456, b_s2, w_t2, w_pl2, out);
  conv_level_k<16, 32, 8, 192><<<dim3(2, 64), dim3(256), 0, stream>>>(
      xp3, wp + 294912, b_s3, w_t3, w_pl3, out);
  level4_k<<<dim3(64, 4), dim3(256), 0, stream>>>(p5, w_t4, w_pl4, out);
}

// Round 3
// 680.074 us; speedup vs baseline: 1.4595x; 1.0312x over previous
//
#include <hip/hip_runtime.h>

// ============================================================================
// ps_component round 3: fully fused conv (no X prepass).
//  - conv_level_k reads fp32 NCHW directly with coalesced scalar loads,
//    converts to bf16 in-register, stages to LDS [qg][row][pos][16B]
//    (pos stride 16B -> bank-uniform, conflict-free read+write).
//  - Weights staged LDS via VGPR register-relay double-buffer: next-kh
//    weights loaded from global during compute, ds_write behind a cheap
//    lgkm-only barrier pair (no vmcnt(0) drains in the K-loop).
//  - prep_w converts the three 3x3 weight tensors once to bf16
//    [lvl][chunk][kh][kw][qg][cout][8cin].
// ============================================================================

typedef short s8v __attribute__((ext_vector_type(8)));   // 8 x bf16 bits
typedef float f4v __attribute__((ext_vector_type(4)));

__device__ __forceinline__ unsigned short f32_bf16_rne(float f) {
  union { float f; unsigned int u; } v;
  v.f = f;
  unsigned int u = v.u;
  u += 0x7FFFu + ((u >> 16) & 1u);
  return (unsigned short)(u >> 16);
}

// ---------------- prep W: OIHW fp32 -> [s][chunk][kh][kw][qg][cout][8c] -----
__global__ void prep_w_k(const float* __restrict__ w1,
                         const float* __restrict__ w2,
                         const float* __restrict__ w3,
                         unsigned short* __restrict__ out) {
  int idx = blockIdx.x * 256 + threadIdx.x;   // total 3*4*3*3*4*128*8 = 442368
  if (idx >= 442368) return;
  int i    = idx & 7;
  int cout = (idx >> 3) & 127;
  int t    = idx >> 10;
  int qg = t & 3; t >>= 2;
  int kw = t % 3; t /= 3;
  int kh = t % 3; t /= 3;
  int chunk = t & 3; t >>= 2;
  int s = t;
  const float* w = (s == 0) ? w1 : ((s == 1) ? w2 : w3);
  int cin = chunk * 32 + qg * 8 + i;
  out[idx] = f32_bf16_rne(w[((cout * 128 + cin) * 3 + kh) * 3 + kw]);
}

// ---------------- init: out[b,c] = b_t * sum_h w_pl[h] + b_pl ---------------
__global__ void init_out_k(float* __restrict__ out,
                           const float* bt1, const float* bt2,
                           const float* bt3, const float* bt4,
                           const float* wpl1, const float* bpl1,
                           const float* wpl2, const float* bpl2,
                           const float* wpl3, const float* bpl3,
                           const float* wpl4, const float* bpl4) {
  int idx = blockIdx.x * 256 + threadIdx.x;
  if (idx >= 64 * 240) return;
  int c = idx % 240;
  const float* wpl; const float* bpl; const float* bt; int H;
  if (c < 128)      { wpl = wpl1; bpl = bpl1; bt = bt1; H = 64; }
  else if (c < 192) { wpl = wpl2; bpl = bpl2; bt = bt2; H = 32; }
  else if (c < 224) { wpl = wpl3; bpl = bpl3; bt = bt3; H = 16; }
  else              { wpl = wpl4; bpl = bpl4; bt = bt4; H = 8;  }
  float s = 0.f;
  for (int h = 0; h < H; ++h) s += wpl[h];
  out[idx] = bt[0] * s + bpl[0];
}

// ---------------- level 4: pure linear reduction over p5 --------------------
__global__ void level4_k(const float* __restrict__ p5,
                         const float* __restrict__ w_t4,
                         const float* __restrict__ w_pl4,
                         float* __restrict__ out) {
  int b = blockIdx.x;
  int z = blockIdx.y;                          // c-range [z*128, z*128+128)
  int t = threadIdx.x;
  int w = t & 15, g = t >> 4;                  // g in [0,16)
  const float* base = p5 + (size_t)b * 65536 + z * 16384;
  const float* wt = w_t4 + z * 128;
  float acc = 0.f;
  for (int j = g; j < 1024; j += 16) {         // j = c_local*8 + h
    acc += wt[j >> 3] * w_pl4[j & 7] * base[j * 16 + w];
  }
  acc += __shfl_xor(acc, 16);
  acc += __shfl_xor(acc, 32);
  if ((t & 48) == 0) atomicAdd(&out[b * 240 + 224 + w], acc);
}

// ---------------- fused conv3x3+relu+tidy+pool per level --------------------
// Block: 256 thr (4 waves). M=128 couts x N=256 positions (R rows x W cols).
// K = 4 chunks(32cin) x 9 taps, mfma_f32_16x16x32_bf16.
template<int H, int W, int R, int COLBASE>
__global__ __launch_bounds__(256, 2)
void conv_level_k(const float* __restrict__ p,                // fp32 NCHW
                  const unsigned short* __restrict__ wl,      // [4][3][3][4][128][8]
                  const float* __restrict__ b_s,
                  const float* __restrict__ w_t,
                  const float* __restrict__ w_pl,
                  float* __restrict__ out) {
  constexpr int ROWS = R + 2;
  constexpr int WP = W + 2;
  constexpr int HW = H * W;
  constexpr int NIT = 4 * ROWS * WP;          // X staging items per chunk
  __shared__ __align__(16) unsigned short Xs[4][ROWS][WP][8];
  __shared__ __align__(16) unsigned short Ws[3][4][128][8];

  const int tid = threadIdx.x;
  const int wave = tid >> 6, lane = tid & 63;
  const int lm = lane & 15, q = lane >> 4;
  const int h0 = blockIdx.x * R;
  const int b  = blockIdx.y;

  int rr[4], ww[4], xbase[4];
#pragma unroll
  for (int nt = 0; nt < 4; ++nt) {
    int n = wave * 64 + nt * 16 + lm;
    rr[nt] = n / W;
    ww[nt] = n % W;
    xbase[nt] = ((q * ROWS + rr[nt]) * WP + ww[nt]) * 16;   // byte offset
  }
  const int woff = (q * 128 + lm) * 16;                      // af byte offset

  f4v acc[8][4];
#pragma unroll
  for (int mt = 0; mt < 8; ++mt)
#pragma unroll
    for (int nt = 0; nt < 4; ++nt)
      acc[mt][nt] = (f4v){0.f, 0.f, 0.f, 0.f};

  const s8v Z8 = {0, 0, 0, 0, 0, 0, 0, 0};
  const float* pb = p + (size_t)b * 128 * HW;
  const char* XsB = (const char*)&Xs[0][0][0][0];
  const char* WsB = (const char*)&Ws[0][0][0][0];

  // ---- weight register relay: 6 segments of 1KB per wave ----
  s8v wreg[6];
  const unsigned short* wseg = wl + wave * 512 + lane * 8;
  unsigned short* wdst = &Ws[0][0][0][0] + wave * 512 + lane * 8;

#define LOAD_W(chunk, kh) do {                                        \
    const unsigned short* _s = wseg + ((chunk) * 3 + (kh)) * 12288;   \
    _Pragma("unroll")                                                 \
    for (int s = 0; s < 6; ++s) wreg[s] = *(const s8v*)(_s + s * 2048); \
  } while (0)

#define STORE_W() do {                                                \
    _Pragma("unroll")                                                 \
    for (int s = 0; s < 6; ++s) *(s8v*)(wdst + s * 2048) = wreg[s];   \
  } while (0)

  LOAD_W(0, 0);

  for (int chunk = 0; chunk < 4; ++chunk) {
    __syncthreads();     // prior iteration's reads of Xs/Ws complete
    // ---- stage X chunk: coalesced fp32 loads, convert, ds_write_b128 ----
    for (int it = tid; it < NIT; it += 256) {
      int pos = it % WP;
      int rem = it / WP;
      int row = rem % ROWS;
      int qg  = rem / ROWS;
      int h_in = h0 + row - 1;
      int w_g  = pos - 1;
      s8v v = Z8;
      if (h_in >= 0 && h_in < H && w_g >= 0 && w_g < W) {
        const float* src = pb + (size_t)(chunk * 32 + qg * 8) * HW + h_in * W + w_g;
#pragma unroll
        for (int i = 0; i < 8; ++i) v[i] = (short)f32_bf16_rne(src[(size_t)i * HW]);
      }
      *(s8v*)&Xs[qg][row][pos][0] = v;
    }
    STORE_W();           // W(chunk, 0), loaded during previous compute
    __syncthreads();

#pragma unroll
    for (int kh = 0; kh < 3; ++kh) {
      // prefetch next (chunk,kh) weights into registers (overlaps compute)
      int nc = (kh == 2) ? ((chunk < 3) ? chunk + 1 : 3) : chunk;
      int nk = (kh == 2) ? 0 : kh + 1;
      LOAD_W(nc, nk);

      int xk[4];
#pragma unroll
      for (int nt = 0; nt < 4; ++nt) xk[nt] = xbase[nt] + kh * (WP * 16);

#pragma unroll
      for (int kw = 0; kw < 3; ++kw) {
        s8v bf[4];
#pragma unroll
        for (int nt = 0; nt < 4; ++nt)
          bf[nt] = *(const s8v*)(XsB + xk[nt] + kw * 16);
#pragma unroll
        for (int mt = 0; mt < 8; ++mt) {
          s8v af = *(const s8v*)(WsB + kw * 8192 + mt * 256 + woff);
#pragma unroll
          for (int nt = 0; nt < 4; ++nt)
            acc[mt][nt] = __builtin_amdgcn_mfma_f32_16x16x32_bf16(af, bf[nt], acc[mt][nt], 0, 0, 0);
        }
      }
      if (kh < 2) {
        __syncthreads();   // compute reads of Ws done
        STORE_W();         // W(chunk, kh+1)
        __syncthreads();   // Ws visible
      }
    }
  }
#undef LOAD_W
#undef STORE_W

  // epilogue: bias+relu+tidy weight, pool weight, quad-reduce, atomic add
#pragma unroll
  for (int nt = 0; nt < 4; ++nt) {
    float s = 0.f;
#pragma unroll
    for (int mt = 0; mt < 8; ++mt) {
#pragma unroll
      for (int rg = 0; rg < 4; ++rg) {
        int cout = mt * 16 + q * 4 + rg;
        float v = fmaxf(acc[mt][nt][rg] + b_s[cout], 0.f);
        s = fmaf(w_t[cout], v, s);
      }
    }
    s *= w_pl[h0 + rr[nt]];
    s += __shfl_xor(s, 16);
    s += __shfl_xor(s, 32);
    if (lane < 16) atomicAdd(&out[b * 240 + COLBASE + ww[nt]], s);
  }
}

// ============================================================================
extern "C" void kernel_launch(void* const* d_in, const int* in_sizes, int n_in,
                              void* d_out, int out_size, void* d_ws, size_t ws_size,
                              hipStream_t stream) {
  (void)in_sizes; (void)n_in; (void)out_size; (void)ws_size;
  const float* p2   = (const float*)d_in[0];
  const float* p3   = (const float*)d_in[1];
  const float* p4   = (const float*)d_in[2];
  const float* p5   = (const float*)d_in[3];
  const float* w_s1 = (const float*)d_in[4];
  const float* b_s1 = (const float*)d_in[5];
  const float* w_s2 = (const float*)d_in[6];
  const float* b_s2 = (const float*)d_in[7];
  const float* w_s3 = (const float*)d_in[8];
  const float* b_s3 = (const float*)d_in[9];
  const float* w_t1 = (const float*)d_in[10];
  const float* b_t1 = (const float*)d_in[11];
  const float* w_t2 = (const float*)d_in[12];
  const float* b_t2 = (const float*)d_in[13];
  const float* w_t3 = (const float*)d_in[14];
  const float* b_t3 = (const float*)d_in[15];
  const float* w_t4 = (const float*)d_in[16];
  const float* b_t4 = (const float*)d_in[17];
  const float* w_pl1 = (const float*)d_in[18];
  const float* b_pl1 = (const float*)d_in[19];
  const float* w_pl2 = (const float*)d_in[20];
  const float* b_pl2 = (const float*)d_in[21];
  const float* w_pl3 = (const float*)d_in[22];
  const float* b_pl3 = (const float*)d_in[23];
  const float* w_pl4 = (const float*)d_in[24];
  const float* b_pl4 = (const float*)d_in[25];

  unsigned short* wp = (unsigned short*)d_ws;   // 442368 shorts = 884736 B
  float* out = (float*)d_out;

  prep_w_k<<<dim3(1728), dim3(256), 0, stream>>>(w_s1, w_s2, w_s3, wp);
  init_out_k<<<dim3(60), dim3(256), 0, stream>>>(out, b_t1, b_t2, b_t3, b_t4,
                                                 w_pl1, b_pl1, w_pl2, b_pl2,
                                                 w_pl3, b_pl3, w_pl4, b_pl4);
  conv_level_k<64, 128, 2, 0><<<dim3(32, 64), dim3(256), 0, stream>>>(
      p2, wp, b_s1, w_t1, w_pl1, out);
  conv_level_k<32, 64, 4, 128><<<dim3(8, 64), dim3(256), 0, stream>>>(
      p3, wp + 147456, b_s2, w_t2, w_pl2, out);
  conv_level_k<16, 32, 8, 192><<<dim3(2, 64), dim3(256), 0, stream>>>(
      p4, wp + 294912, b_s3, w_t3, w_pl3, out);
  level4_k<<<dim3(64, 4), dim3(256), 0, stream>>>(p5, w_t4, w_pl4, out);
}

// Round 4
// 648.351 us; speedup vs baseline: 1.5309x; 1.0489x over previous
//
#include <hip/hip_runtime.h>

// ============================================================================
// ps_component round 4: single-barrier-per-stage fused conv.
//  - R=1 row strips; rolling X-row staging (one row written per stage into the
//    slot freed by the previous stage) -> single X buffer, no extra barriers.
//  - Ws double-buffered -> W relay needs no mid-stage barriers.
//  - All global loads prefetched into VGPRs one stage ahead; barriers are raw
//    "s_waitcnt lgkmcnt(0); s_barrier" (no vmcnt drain; global loads are
//    register-private, only ds_writes need cross-wave visibility).
//  - 12 stages/block, each: writeW(next) + writeX(row) + issue next loads +
//    48 MFMAs + 1 barrier.
// ============================================================================

typedef short s8v __attribute__((ext_vector_type(8)));   // 8 x bf16 bits
typedef float f4v __attribute__((ext_vector_type(4)));

#define BARRIER() asm volatile("s_waitcnt lgkmcnt(0)\n\ts_barrier" ::: "memory")

__device__ __forceinline__ unsigned short f32_bf16_rne(float f) {
  union { float f; unsigned int u; } v;
  v.f = f;
  unsigned int u = v.u;
  u += 0x7FFFu + ((u >> 16) & 1u);
  return (unsigned short)(u >> 16);
}

// ---------------- prep W: OIHW fp32 -> [s][chunk][kh][kw][qg][cout][8c] -----
__global__ void prep_w_k(const float* __restrict__ w1,
                         const float* __restrict__ w2,
                         const float* __restrict__ w3,
                         unsigned short* __restrict__ out) {
  int idx = blockIdx.x * 256 + threadIdx.x;   // total 3*4*3*3*4*128*8 = 442368
  if (idx >= 442368) return;
  int i    = idx & 7;
  int cout = (idx >> 3) & 127;
  int t    = idx >> 10;
  int qg = t & 3; t >>= 2;
  int kw = t % 3; t /= 3;
  int kh = t % 3; t /= 3;
  int chunk = t & 3; t >>= 2;
  int s = t;
  const float* w = (s == 0) ? w1 : ((s == 1) ? w2 : w3);
  int cin = chunk * 32 + qg * 8 + i;
  out[idx] = f32_bf16_rne(w[((cout * 128 + cin) * 3 + kh) * 3 + kw]);
}

// ---------------- init: out[b,c] = b_t * sum_h w_pl[h] + b_pl ---------------
__global__ void init_out_k(float* __restrict__ out,
                           const float* bt1, const float* bt2,
                           const float* bt3, const float* bt4,
                           const float* wpl1, const float* bpl1,
                           const float* wpl2, const float* bpl2,
                           const float* wpl3, const float* bpl3,
                           const float* wpl4, const float* bpl4) {
  int idx = blockIdx.x * 256 + threadIdx.x;
  if (idx >= 64 * 240) return;
  int c = idx % 240;
  const float* wpl; const float* bpl; const float* bt; int H;
  if (c < 128)      { wpl = wpl1; bpl = bpl1; bt = bt1; H = 64; }
  else if (c < 192) { wpl = wpl2; bpl = bpl2; bt = bt2; H = 32; }
  else if (c < 224) { wpl = wpl3; bpl = bpl3; bt = bt3; H = 16; }
  else              { wpl = wpl4; bpl = bpl4; bt = bt4; H = 8;  }
  float s = 0.f;
  for (int h = 0; h < H; ++h) s += wpl[h];
  out[idx] = bt[0] * s + bpl[0];
}

// ---------------- level 4: pure linear reduction over p5 --------------------
__global__ void level4_k(const float* __restrict__ p5,
                         const float* __restrict__ w_t4,
                         const float* __restrict__ w_pl4,
                         float* __restrict__ out) {
  int b = blockIdx.x;
  int z = blockIdx.y;                          // c-range [z*128, z*128+128)
  int t = threadIdx.x;
  int w = t & 15, g = t >> 4;                  // g in [0,16)
  const float* base = p5 + (size_t)b * 65536 + z * 16384;
  const float* wt = w_t4 + z * 128;
  float acc = 0.f;
  for (int j = g; j < 1024; j += 16) {         // j = c_local*8 + h
    acc += wt[j >> 3] * w_pl4[j & 7] * base[j * 16 + w];
  }
  acc += __shfl_xor(acc, 16);
  acc += __shfl_xor(acc, 32);
  if ((t & 48) == 0) atomicAdd(&out[b * 240 + 224 + w], acc);
}

// ---------------- fused conv3x3+relu+tidy+pool per level --------------------
// Block: 256 thr. M=128 couts x N=W positions (1 row). 12 stages (4 chunks x
// 3 kh), mfma_f32_16x16x32_bf16, 1 barrier per stage.
template<int H, int W, int COLBASE>
__global__ __launch_bounds__(256, 2)
void conv_fused_k(const float* __restrict__ p,
                  const unsigned short* __restrict__ wl,  // [4][3][3][4][128][8]
                  const float* __restrict__ b_s,
                  const float* __restrict__ w_t,
                  const float* __restrict__ w_pl,
                  float* __restrict__ out) {
  constexpr int WP = W + 2;
  constexpr int NT = (W >= 128) ? 2 : 1;       // N-tiles per wave
  constexpr int AW = W / (16 * NT);            // active compute waves
  constexpr int HW = H * W;
  constexpr int SLOTS = 4 * W;                 // staging slots per row
  constexpr int SPT = (SLOTS + 255) / 256;     // slots per thread
  __shared__ __align__(16) unsigned short Xs[4][3][WP][8];        // [qg][row][pos][8c]
  __shared__ __align__(16) unsigned short Ws[2][3][4][128][8];    // [buf][kw][qg][cout][8c]

  const int tid = threadIdx.x;
  const int wave = tid >> 6, lane = tid & 63;
  const int lm = lane & 15, q = lane >> 4;
  const int h0 = blockIdx.x;
  const int b  = blockIdx.y;
  const float* pb = p + (size_t)b * 128 * HW;

  // ---- staging slot precompute (constant across stages) ----
  int sqg[SPT], swp[SPT];
  bool sok[SPT];
  const float* sbase[SPT];
#pragma unroll
  for (int k = 0; k < SPT; ++k) {
    int slot = tid + 256 * k;
    sok[k] = (SLOTS % 256 == 0) ? true : (slot < SLOTS);
    int qg = slot / W;
    int wp_ = slot % W;
    sqg[k] = qg; swp[k] = wp_;
    sbase[k] = pb + (size_t)(qg * 8) * HW + wp_;
  }
  bool rok[3]; int hin[3];
#pragma unroll
  for (int r = 0; r < 3; ++r) { hin[r] = h0 + r - 1; rok[r] = (hin[r] >= 0) && (hin[r] < H); }

  float xf[SPT][8];
  s8v wreg[6];
  const unsigned short* wseg = wl + wave * 512 + lane * 8;
  unsigned short* wdstbase = &Ws[0][0][0][0][0] + wave * 512 + lane * 8;

  auto issueW = [&](int t) {
    const unsigned short* s = wseg + t * 12288;
#pragma unroll
    for (int j = 0; j < 6; ++j) wreg[j] = *(const s8v*)(s + j * 2048);
  };
  auto writeW = [&](int buf) {
    unsigned short* d = wdstbase + buf * 12288;
#pragma unroll
    for (int j = 0; j < 6; ++j) *(s8v*)(d + j * 2048) = wreg[j];
  };
  auto issueXa = [&](float (*arr)[8], int c, int r) {
#pragma unroll
    for (int k = 0; k < SPT; ++k) {
      if (sok[k] && rok[r]) {
        const float* s = sbase[k] + (size_t)(c * 32) * HW + (size_t)hin[r] * W;
#pragma unroll
        for (int i = 0; i < 8; ++i) arr[k][i] = s[(size_t)i * HW];
      } else {
#pragma unroll
        for (int i = 0; i < 8; ++i) arr[k][i] = 0.f;
      }
    }
  };
  auto writeXa = [&](float (*arr)[8], int r) {
#pragma unroll
    for (int k = 0; k < SPT; ++k) {
      if (sok[k]) {
        s8v v;
#pragma unroll
        for (int i = 0; i < 8; ++i) v[i] = (short)f32_bf16_rne(arr[k][i]);
        *(s8v*)&Xs[sqg[k]][r][1 + swp[k]][0] = v;
      }
    }
  };

  // ---- prologue: zero halo cols, stage rows 0,1, W batch 0; issue row2 + W1
  if (tid < 24) {
    int qg = tid / 6, r2 = tid % 6;
    const s8v Z = {0, 0, 0, 0, 0, 0, 0, 0};
    *(s8v*)&Xs[qg][r2 >> 1][(r2 & 1) ? (WP - 1) : 0][0] = Z;
  }
  {
    float xr0[SPT][8], xr1[SPT][8];
    issueW(0);
    issueXa(xr0, 0, 0);
    issueXa(xr1, 0, 1);
    issueXa(xf, 0, 2);        // row2(c0), consumed at stage (0,0)
    writeW(0);                // -> Ws[0]
    issueW(1);
    writeXa(xr0, 0);
    writeXa(xr1, 1);
  }
  BARRIER();

  f4v acc[8][NT];
#pragma unroll
  for (int mt = 0; mt < 8; ++mt)
#pragma unroll
    for (int t = 0; t < NT; ++t)
      acc[mt][t] = (f4v){0.f, 0.f, 0.f, 0.f};

  // ---- 12 stages ----
  for (int c = 0; c < 4; ++c) {
#pragma unroll
    for (int kh = 0; kh < 3; ++kh) {
      const int sidx = c * 3 + kh;
      // W relay: write batch sidx+1 (loaded last stage) into other buffer
      if (!(c == 3 && kh == 2)) writeW((sidx + 1) & 1);
      if (!(c == 3 && kh >= 1)) issueW(sidx + 2);
      // X rolling-row write + next-issue
      if (kh == 0) {
        writeXa(xf, 2);                       // row2(c), issued last stage
        if (c < 3) issueXa(xf, c + 1, 0);
      } else if (kh == 1) {
        if (c < 3) { writeXa(xf, 0); issueXa(xf, c + 1, 1); }
      } else {
        if (c < 3) { writeXa(xf, 1); issueXa(xf, c + 1, 2); }
      }
      // compute: reads Xs row kh, Ws[sidx&1]
      if (wave < AW) {
        const unsigned short* WsRd = &Ws[sidx & 1][0][0][0][0];
#pragma unroll
        for (int kw = 0; kw < 3; ++kw) {
          s8v bfv[NT];
#pragma unroll
          for (int t = 0; t < NT; ++t) {
            int n = wave * (16 * NT) + t * 16 + lm;
            bfv[t] = *(const s8v*)&Xs[q][kh][n + kw][0];
          }
#pragma unroll
          for (int mt = 0; mt < 8; ++mt) {
            s8v af = *(const s8v*)(WsRd + kw * 4096 + q * 1024 + (mt * 16 + lm) * 8);
#pragma unroll
            for (int t = 0; t < NT; ++t)
              acc[mt][t] = __builtin_amdgcn_mfma_f32_16x16x32_bf16(af, bfv[t], acc[mt][t], 0, 0, 0);
          }
        }
      }
      if (!(c == 3 && kh == 2)) BARRIER();
    }
  }

  // ---- epilogue: bias+relu+tidy, pool weight, quad-reduce, atomic add ----
  if (wave < AW) {
    const float wph = w_pl[h0];
#pragma unroll
    for (int t = 0; t < NT; ++t) {
      float s = 0.f;
#pragma unroll
      for (int mt = 0; mt < 8; ++mt) {
#pragma unroll
        for (int rg = 0; rg < 4; ++rg) {
          int cout = mt * 16 + q * 4 + rg;
          float v = fmaxf(acc[mt][t][rg] + b_s[cout], 0.f);
          s = fmaf(w_t[cout], v, s);
        }
      }
      s *= wph;
      s += __shfl_xor(s, 16);
      s += __shfl_xor(s, 32);
      int n = wave * (16 * NT) + t * 16 + lm;
      if (lane < 16) atomicAdd(&out[b * 240 + COLBASE + n], s);
    }
  }
}

// ============================================================================
extern "C" void kernel_launch(void* const* d_in, const int* in_sizes, int n_in,
                              void* d_out, int out_size, void* d_ws, size_t ws_size,
                              hipStream_t stream) {
  (void)in_sizes; (void)n_in; (void)out_size; (void)ws_size;
  const float* p2   = (const float*)d_in[0];
  const float* p3   = (const float*)d_in[1];
  const float* p4   = (const float*)d_in[2];
  const float* p5   = (const float*)d_in[3];
  const float* w_s1 = (const float*)d_in[4];
  const float* b_s1 = (const float*)d_in[5];
  const float* w_s2 = (const float*)d_in[6];
  const float* b_s2 = (const float*)d_in[7];
  const float* w_s3 = (const float*)d_in[8];
  const float* b_s3 = (const float*)d_in[9];
  const float* w_t1 = (const float*)d_in[10];
  const float* b_t1 = (const float*)d_in[11];
  const float* w_t2 = (const float*)d_in[12];
  const float* b_t2 = (const float*)d_in[13];
  const float* w_t3 = (const float*)d_in[14];
  const float* b_t3 = (const float*)d_in[15];
  const float* w_t4 = (const float*)d_in[16];
  const float* b_t4 = (const float*)d_in[17];
  const float* w_pl1 = (const float*)d_in[18];
  const float* b_pl1 = (const float*)d_in[19];
  const float* w_pl2 = (const float*)d_in[20];
  const float* b_pl2 = (const float*)d_in[21];
  const float* w_pl3 = (const float*)d_in[22];
  const float* b_pl3 = (const float*)d_in[23];
  const float* w_pl4 = (const float*)d_in[24];
  const float* b_pl4 = (const float*)d_in[25];

  unsigned short* wp = (unsigned short*)d_ws;   // 442368 shorts = 884736 B
  float* out = (float*)d_out;

  prep_w_k<<<dim3(1728), dim3(256), 0, stream>>>(w_s1, w_s2, w_s3, wp);
  init_out_k<<<dim3(60), dim3(256), 0, stream>>>(out, b_t1, b_t2, b_t3, b_t4,
                                                 w_pl1, b_pl1, w_pl2, b_pl2,
                                                 w_pl3, b_pl3, w_pl4, b_pl4);
  conv_fused_k<64, 128, 0><<<dim3(64, 64), dim3(256), 0, stream>>>(
      p2, wp, b_s1, w_t1, w_pl1, out);
  conv_fused_k<32, 64, 128><<<dim3(32, 64), dim3(256), 0, stream>>>(
      p3, wp + 147456, b_s2, w_t2, w_pl2, out);
  conv_fused_k<16, 32, 192><<<dim3(16, 64), dim3(256), 0, stream>>>(
      p4, wp + 294912, b_s3, w_t3, w_pl3, out);
  level4_k<<<dim3(64, 4), dim3(256), 0, stream>>>(p5, w_t4, w_pl4, out);
}